// Round 7
// baseline (1678.800 us; speedup 1.0000x reference)
//
#include <hip/hip_runtime.h>
#include <hip/hip_bf16.h>

// B=256, L=2048, H=128, V=32000, THR=0.4, LN_EPS=1e-5. All fp32.
// Htab2 row (RS=136 floats): [0:64)=h[0..63], [64:68)=pad, [68:132)=h[64..127],
// [132]=kk, [133]=inv.
// Scan v6b ("one-behind" pipeline; identical to v6, resubmitted after infra
// failure): at step t,
//   PRE : e_t = fma(-inv_t, vpb_t, k_t[i]) - ac*e_{t-1}   (ac = inv_t*g_{t-1}*c_{t-1,t})
//         trees{ ||e_t||^2, c_t = k_t.k_{t+1} } -> red write -> barrier
//   POST: M += g_{t-1} e_{t-1} k_{t-1}  (gate known LAST step: no red dep)
//         vpb_{t+1} = M_{t-1} k_{t+1}   (kN refilled LAST step: no LDS dep)
//         red read -> g_t (parallel with update+matvec); refill k_{t+2}->kO.
// Nothing between barriers waits on same-step LDS. Exact algebra (rank-1
// lookahead, verified family v2/v5). 6-slot ring, lead-4 DMA, vmcnt(4).

#define BB 256
#define LL 2048
#define HH 128
#define VV 32000
#define RS 136

typedef float f32x2 __attribute__((ext_vector_type(2)));

__device__ __forceinline__ void dma16(const float* g, float* l) {
  __builtin_amdgcn_global_load_lds(
      (const __attribute__((address_space(1))) void*)g,
      (__attribute__((address_space(3))) void*)l,
      16, 0, 0);
}

template <int CTRL>
__device__ __forceinline__ float dppadd(float x) {
  int y = __builtin_amdgcn_update_dpp(0, __float_as_int(x), CTRL, 0xF, 0xF, true);
  return x + __int_as_float(y);
}

// d = a*b + d  (packed 2x fp32)
__device__ __forceinline__ void pkfma(f32x2& d, f32x2 a, f32x2 b) {
  asm("v_pk_fma_f32 %0, %1, %2, %0" : "+v"(d) : "v"(a), "v"(b));
}

__device__ __forceinline__ void barrier_lgkm() {
  asm volatile("s_waitcnt lgkmcnt(0)\n\ts_barrier" ::: "memory");
}
__device__ __forceinline__ void wait_vmN(int n) {
  if (n == 4)      asm volatile("s_waitcnt vmcnt(4)" ::: "memory");
  else if (n == 3) asm volatile("s_waitcnt vmcnt(3)" ::: "memory");
  else if (n == 2) asm volatile("s_waitcnt vmcnt(2)" ::: "memory");
  else if (n == 1) asm volatile("s_waitcnt vmcnt(1)" ::: "memory");
  else             asm volatile("s_waitcnt vmcnt(0)" ::: "memory");
}

// ---------------------------------------------------------------------------
// Kernel A: Htab2 row = LN(e + relu(e@W1+b1)@W2 + b2) (+ kk, inv), padded.
// (unchanged from verified baseline)
// ---------------------------------------------------------------------------
__global__ __launch_bounds__(256, 1) void build_htab_kernel(
    const float* __restrict__ embed,
    const float* __restrict__ W1,
    const float* __restrict__ b1,
    const float* __restrict__ W2,
    const float* __restrict__ b2,
    const float* __restrict__ gamma,
    const float* __restrict__ beta,
    float* __restrict__ Htab2)
{
  const int tid = threadIdx.x;
  const int j   = tid & 127;
  const int h2  = tid >> 7;

  float w1r[128];
#pragma unroll
  for (int m = 0; m < 128; ++m) w1r[m] = W1[m * 256 + tid];

  const float b1n = b1[tid];
  const float b2j = b2[j];
  const float gj  = gamma[j];
  const float bj  = beta[j];

  __shared__ __align__(16) float4 w2q[64][128];   // 128 KiB
  __shared__ __align__(16) float e_s[128];
  __shared__ __align__(16) float a_s[256];
  __shared__ float p_s[2][128];
  __shared__ float red[8];

  for (int idx = tid; idx < 8192; idx += 256) {
    int n4 = idx >> 7, jj = idx & 127;
    float4 w;
    w.x = W2[(size_t)(4 * n4 + 0) * 128 + jj];
    w.y = W2[(size_t)(4 * n4 + 1) * 128 + jj];
    w.z = W2[(size_t)(4 * n4 + 2) * 128 + jj];
    w.w = W2[(size_t)(4 * n4 + 3) * 128 + jj];
    w2q[n4][jj] = w;
  }
  __syncthreads();

  for (int v = blockIdx.x; v < VV; v += gridDim.x) {
    if (tid < 128) e_s[tid] = embed[(size_t)v * 128 + tid];
    __syncthreads();

    float acc[4] = {b1n, 0.f, 0.f, 0.f};
#pragma unroll
    for (int q = 0; q < 32; ++q) {
      float4 ev = *(const float4*)&e_s[4 * q];
      float t = ev.x * w1r[4 * q + 0];
      t = fmaf(ev.y, w1r[4 * q + 1], t);
      t = fmaf(ev.z, w1r[4 * q + 2], t);
      t = fmaf(ev.w, w1r[4 * q + 3], t);
      acc[q & 3] += t;
    }
    float a = fmaxf((acc[0] + acc[1]) + (acc[2] + acc[3]), 0.0f);
    a_s[tid] = a;
    __syncthreads();

    float p0 = 0.f, p1 = 0.f, p2v = 0.f, p3 = 0.f;
#pragma unroll
    for (int q = 0; q < 32; ++q) {
      int n4 = h2 * 32 + q;
      float4 av = *(const float4*)&a_s[4 * n4];
      float4 wq = w2q[n4][j];
      p0 = fmaf(av.x, wq.x, p0);
      p1 = fmaf(av.y, wq.y, p1);
      p2v = fmaf(av.z, wq.z, p2v);
      p3 = fmaf(av.w, wq.w, p3);
    }
    p_s[h2][j] = (p0 + p1) + (p2v + p3);
    __syncthreads();

    float y = 0.0f;
    if (tid < 128) {
      float ff = p_s[0][tid] + p_s[1][tid] + b2j;
      y = e_s[tid] + ff;
    }
    float s1 = y, s2 = y * y;
    s1 = dppadd<0xB1>(s1);  s2 = dppadd<0xB1>(s2);
    s1 = dppadd<0x4E>(s1);  s2 = dppadd<0x4E>(s2);
    s1 = dppadd<0x141>(s1); s2 = dppadd<0x141>(s2);
    s1 = dppadd<0x140>(s1); s2 = dppadd<0x140>(s2);
    s1 = dppadd<0x142>(s1); s2 = dppadd<0x142>(s2);
    s1 = dppadd<0x143>(s1); s2 = dppadd<0x143>(s2);
    if (tid < 128 && (tid & 63) == 63) {
      red[tid >> 6] = s1;
      red[2 + (tid >> 6)] = s2;
    }
    __syncthreads();
    float mu = (red[0] + red[1]) * (1.0f / 128.0f);
    float ms = (red[2] + red[3]) * (1.0f / 128.0f);
    float var = ms - mu * mu;
    float hv = 0.0f;
    if (tid < 128) {
      float dy = y - mu;
      hv = dy * (1.0f / sqrtf(var + 1e-5f)) * gj + bj;
      int ofs = tid + ((tid >> 6) << 2);           // padded layout
      Htab2[(size_t)v * RS + ofs] = hv;
    }
    float q2 = hv * hv;
    q2 = dppadd<0xB1>(q2);
    q2 = dppadd<0x4E>(q2);
    q2 = dppadd<0x141>(q2);
    q2 = dppadd<0x140>(q2);
    q2 = dppadd<0x142>(q2);
    q2 = dppadd<0x143>(q2);
    if (tid < 128 && (tid & 63) == 63) red[4 + (tid >> 6)] = q2;
    __syncthreads();
    if (tid == 0) {
      float kk = red[4] + red[5];
      Htab2[(size_t)v * RS + 132] = kk;
      Htab2[(size_t)v * RS + 133] = 1.0f / (kk + 1e-6f);
    }
    __syncthreads();
  }
}

// ---------------------------------------------------------------------------
// Kernel B: per-batch scan, "one-behind" pipeline. 256 blocks x 512 threads.
// Thread (i=tid>>2, q=tid&3) owns M[i][32q..32q+32) as 16 f32x2.
// Buffers: kO=k_{t-1} (update operand; refilled to k_{t+2} after use),
//          kC=k_t (trees), kN=k_{t+1} (matvec operand, loaded LAST step).
// Slot j%6 holds k_j; DMA k_{t+6} issued at t PRE; vmcnt(4) at t POST
// retires exactly k_{t+2}.
// ---------------------------------------------------------------------------
__global__ __launch_bounds__(512, 1) void scan_kernel(
    const int* __restrict__ seq,
    const float* __restrict__ Htab2,
    const float* __restrict__ Wrp,
    const float* __restrict__ brp,
    float* __restrict__ rr)
{
  const int b     = blockIdx.x;
  const int tid   = threadIdx.x;
  const int i     = tid >> 2;              // row 0..127
  const int q     = tid & 3;               // column quarter
  const int lane  = tid & 63;
  const int wv    = tid >> 6;              // wave 0..7
  const int iofs  = i + ((i >> 6) << 2);   // padded-row index of h[i]
  const int kbase = (q & 1) * 32 + (q >> 1) * 68;  // float offset of own 32 cols

  __shared__ int seq_s[LL];
  __shared__ __align__(16) float slots[6][RS];
  __shared__ __align__(16) float2 red2[3][8];   // {||e||^2, c} per wave
  __shared__ __align__(16) float r_s[128];
  __shared__ float p2_s[4][128];

  // prologue DMAs: k0..k5 -> slots 0..5 (every wave issues its own copy)
  for (int jj = 0; jj < 6; ++jj) {
    int tj = seq[(size_t)b * LL + jj];
    if (lane < 34)
      dma16(Htab2 + (size_t)tj * RS + lane * 4, &slots[jj][0]);
  }
  for (int t = tid; t < LL; t += 512) seq_s[t] = seq[(size_t)b * LL + t];
  __syncthreads();   // full drain (vmcnt+lgkm): all 6 prologue DMAs landed

  f32x2 M2[16];
#pragma unroll
  for (int m = 0; m < 16; ++m) M2[m] = f32x2{0.f, 0.f};

  f32x2 kA[16], kB[16], kC[16];
  float kiA = 0.f, kkA = 0.f, invA = 0.f;    // "k_{-1}" (unused: ge=0)
  float kiB, kkB, invB, kiC, kkC, invC;
#pragma unroll
  for (int m = 0; m < 16; ++m) kA[m] = f32x2{0.f, 0.f};
  {
    const float4* kp = (const float4*)&slots[0][kbase];   // k_0 -> kB
#pragma unroll
    for (int m = 0; m < 8; ++m) {
      float4 tq = kp[m];
      kB[2 * m]     = f32x2{tq.x, tq.y};
      kB[2 * m + 1] = f32x2{tq.z, tq.w};
    }
    kiB = slots[0][iofs];
    float2 kv = *(const float2*)&slots[0][132];
    kkB = kv.x; invB = kv.y;
  }
  {
    const float4* kp = (const float4*)&slots[1][kbase];   // k_1 -> kC
#pragma unroll
    for (int m = 0; m < 8; ++m) {
      float4 tq = kp[m];
      kC[2 * m]     = f32x2{tq.x, tq.y};
      kC[2 * m + 1] = f32x2{tq.z, tq.w};
    }
    kiC = slots[1][iofs];
    float2 kv = *(const float2*)&slots[1][132];
    kkC = kv.x; invC = kv.y;
  }
  // init reads of slots 0/1 must complete in ALL waves before step-0's DMA
  // (k_6 -> slot 0) can land. One extra barrier, once.
  __syncthreads();

  // pipeline state (all wave-uniform except e_prev/ge_prev per-thread rows)
  float e_prev  = 0.f;   // e_{t-1}[i]
  float ge_prev = 0.f;   // g_{t-1} * e_{t-1}[i]
  float ac      = 0.f;   // inv_t * g_{t-1} * c_{t-1,t}
  float vpb     = 0.f;   // (M_{t-1} k_t)[i], quad-replicated
  int   tk      = seq_s[6];

  auto step = [&](f32x2 (&kO)[16], float& kiO, float& kkO, float& invO,
                  f32x2 (&kCc)[16], float& kiCc, float& kkCc, float& invCc,
                  f32x2 (&kN)[16], float& kiN, float& kkN, float& invN,
                  int t, int p, int sread, int sdma, int nwait,
                  int do_issue, int do_pref, int do_refill) {
    // ---- PRE ----
    if (do_issue) {
      if (lane < 34)
        dma16(Htab2 + (size_t)tk * RS + lane * 4, &slots[sdma][0]);
    }
    float e = fmaf(-ac, e_prev, fmaf(-invCc, vpb, kiCc));  // e_t (exact)
    float s  = e * e;                // ||e_t||^2 partial (rows once via tree)
    float c1 = kiCc * kiN;           // c_t = k_t.k_{t+1} partial
    s = dppadd<0x141>(s);  c1 = dppadd<0x141>(c1);
    s = dppadd<0x140>(s);  c1 = dppadd<0x140>(c1);
    s = dppadd<0x142>(s);  c1 = dppadd<0x142>(c1);
    s = dppadd<0x143>(s);  c1 = dppadd<0x143>(c1);
    if (lane == 63) red2[p][wv] = float2{s, c1};
    barrier_lgkm();                  // lgkmcnt(0)+s_barrier, NO vmcnt drain
    __builtin_amdgcn_sched_barrier(0);   // pin the PRE/POST phase split
    // ---- POST ----
    // update M_{t-2} -> M_{t-1}: no red dep (gate from last step)
    {
      f32x2 gev{ge_prev, ge_prev};
#pragma unroll
      for (int m = 0; m < 16; ++m) pkfma(M2[m], gev, kO[m]);
    }
    // red read (issues early; latency overlaps matvec below)
    const float4* rp = (const float4*)&red2[p][0];
    float4 ra = rp[0], rb = rp[1], rc4 = rp[2], rd = rp[3];
    // matvec vpb_{t+1} = M_{t-1} k_{t+1}: kN loaded LAST step (reg-resident)
    f32x2 a0{0.f,0.f}, a1{0.f,0.f}, a2{0.f,0.f}, a3{0.f,0.f};
#pragma unroll
    for (int m = 0; m < 4; ++m) {
      pkfma(a0, kN[4 * m + 0], M2[4 * m + 0]);
      pkfma(a1, kN[4 * m + 1], M2[4 * m + 1]);
      pkfma(a2, kN[4 * m + 2], M2[4 * m + 2]);
      pkfma(a3, kN[4 * m + 3], M2[4 * m + 3]);
    }
    float nv = ((a0.x + a0.y) + (a1.x + a1.y)) + ((a2.x + a2.y) + (a3.x + a3.y));
    nv = dppadd<0xB1>(nv);
    nv = dppadd<0x4E>(nv);           // full row dot, quad-replicated
    // refill kO <- k_{t+2} (consumed only NEXT step: full barrier of slack)
    if (do_refill) {
      wait_vmN(nwait);
      const float4* kp = (const float4*)&slots[sread][kbase];
#pragma unroll
      for (int m = 0; m < 8; ++m) {
        float4 tq = kp[m];
        kO[2 * m]     = f32x2{tq.x, tq.y};
        kO[2 * m + 1] = f32x2{tq.z, tq.w};
      }
      kiO = slots[sread][iofs];
      float2 kv = *(const float2*)&slots[sread][132];
      kkO = kv.x; invO = kv.y;
    }
    if (do_pref) tk = seq_s[t + 7];
    // gate g_t (parallel branch off the red read)
    float ne2 = ((ra.x + ra.z) + (rb.x + rb.z)) + ((rc4.x + rc4.z) + (rd.x + rd.z));
    float cs  = ((ra.y + ra.w) + (rb.y + rb.w)) + ((rc4.y + rc4.w) + (rd.y + rd.w));
    int  g  = ne2 > 0.16f * kkCc;    // ||e_t|| > 0.4*||v_t|| (squared form)
    ge_prev = g ? e : 0.0f;
    ac      = g ? (invN * cs) : 0.0f;
    e_prev  = e;
    vpb     = nv;
  };

  // main loop t=0..2039 (2040 = 6*340); buffers period 3, slots period 6.
  for (int t = 0; t < 2040; t += 6) {
    step(kA,kiA,kkA,invA, kB,kiB,kkB,invB, kC,kiC,kkC,invC, t+0, 0, 2, 0, 4, 1,1,1);
    step(kB,kiB,kkB,invB, kC,kiC,kkC,invC, kA,kiA,kkA,invA, t+1, 1, 3, 1, 4, 1,1,1);
    step(kC,kiC,kkC,invC, kA,kiA,kkA,invA, kB,kiB,kkB,invB, t+2, 2, 4, 2, 4, 1,1,1);
    step(kA,kiA,kkA,invA, kB,kiB,kkB,invB, kC,kiC,kkC,invC, t+3, 0, 5, 3, 4, 1,1,1);
    step(kB,kiB,kkB,invB, kC,kiC,kkC,invC, kA,kiA,kkA,invA, t+4, 1, 0, 4, 4, 1,1,1);
    step(kC,kiC,kkC,invC, kA,kiA,kkA,invA, kB,kiB,kkB,invB, t+5, 2, 1, 5, 4, 1,1,1);
  }
  // tail t=2040..2045: last DMA at t=2041 (k_2047); drain vmcnt 4->0
  step(kA,kiA,kkA,invA, kB,kiB,kkB,invB, kC,kiC,kkC,invC, 2040, 0, 2, 0, 4, 1,1,1);
  step(kB,kiB,kkB,invB, kC,kiC,kkC,invC, kA,kiA,kkA,invA, 2041, 1, 3, 1, 4, 1,0,1);
  step(kC,kiC,kkC,invC, kA,kiA,kkA,invA, kB,kiB,kkB,invB, 2042, 2, 4, 2, 3, 0,0,1);
  step(kA,kiA,kkA,invA, kB,kiB,kkB,invB, kC,kiC,kkC,invC, 2043, 0, 5, 3, 2, 0,0,1);
  step(kB,kiB,kkB,invB, kC,kiC,kkC,invC, kA,kiA,kkA,invA, 2044, 1, 0, 4, 1, 0,0,1);
  step(kC,kiC,kkC,invC, kA,kiA,kkA,invA, kB,kiB,kkB,invB, 2045, 2, 1, 5, 0, 0,0,1);
  // final step t=2046 inline: kO=kA=k_2045, kC=kB=k_2046, kN=kC=k_2047
  {
    float e = fmaf(-ac, e_prev, fmaf(-invB, vpb, kiB));    // e_2046
    float s  = e * e;
    float c1 = kiB * kiC;            // k_2046 . k_2047
    s = dppadd<0x141>(s);  c1 = dppadd<0x141>(c1);
    s = dppadd<0x140>(s);  c1 = dppadd<0x140>(c1);
    s = dppadd<0x142>(s);  c1 = dppadd<0x142>(c1);
    s = dppadd<0x143>(s);  c1 = dppadd<0x143>(c1);
    if (lane == 63) red2[0][wv] = float2{s, c1};
    barrier_lgkm();
    __builtin_amdgcn_sched_barrier(0);
    {
      f32x2 gev{ge_prev, ge_prev};   // apply g_2045 e_2045 k_2045
#pragma unroll
      for (int m = 0; m < 16; ++m) pkfma(M2[m], gev, kA[m]);
    }
    const float4* rp = (const float4*)&red2[0][0];
    float4 ra = rp[0], rb = rp[1], rc4 = rp[2], rd = rp[3];
    f32x2 a0{0.f,0.f}, a1{0.f,0.f}, a2{0.f,0.f}, a3{0.f,0.f};
#pragma unroll
    for (int m = 0; m < 4; ++m) {
      pkfma(a0, kC[4 * m + 0], M2[4 * m + 0]);   // M_2045 k_2047
      pkfma(a1, kC[4 * m + 1], M2[4 * m + 1]);
      pkfma(a2, kC[4 * m + 2], M2[4 * m + 2]);
      pkfma(a3, kC[4 * m + 3], M2[4 * m + 3]);
    }
    float nv = ((a0.x + a0.y) + (a1.x + a1.y)) + ((a2.x + a2.y) + (a3.x + a3.y));
    nv = dppadd<0xB1>(nv);
    nv = dppadd<0x4E>(nv);
    float ne2 = ((ra.x + ra.z) + (rb.x + rb.z)) + ((rc4.x + rc4.z) + (rd.x + rd.z));
    float cs  = ((ra.y + ra.w) + (rb.y + rb.w)) + ((rc4.y + rc4.w) + (rd.y + rd.w));
    int  g  = ne2 > 0.16f * kkB;
    float gc = g ? cs : 0.0f;
    // r = M_2046 k_2047 = M_2045 k_2047 + g_2046 (k_2046.k_2047) e_2046
    float rres = fmaf(gc, e, nv);
    if (q == 0) r_s[i] = rres;
  }
  __syncthreads();

  // rr[b,:] = r @ Wrp + brp  (512 threads: 4 row-groups of 32)
  const int j = tid & 127;
  const int g = tid >> 7;
  float pac[2] = {0.f, 0.f};
#pragma unroll
  for (int m = 0; m < 32; ++m) {
    pac[m & 1] = fmaf(r_s[g * 32 + m],
                      Wrp[(size_t)(g * 32 + m) * 128 + j], pac[m & 1]);
  }
  p2_s[g][j] = pac[0] + pac[1];
  __syncthreads();
  if (tid < 128) {
    rr[(size_t)b * 128 + tid] =
        p2_s[0][tid] + p2_s[1][tid] + p2_s[2][tid] + p2_s[3][tid] + brp[tid];
  }
}

// ---------------------------------------------------------------------------
// Kernel C: out[b,v] = rr[b,:] @ Wout[:,v] + bout[v]  (unchanged)
// ---------------------------------------------------------------------------
__global__ __launch_bounds__(256, 1) void out_kernel(
    const float* __restrict__ rr,
    const float* __restrict__ Wout,
    const float* __restrict__ bout,
    float* __restrict__ out)
{
  const int tid = threadIdx.x;
  const int v = blockIdx.x * 64 + (tid & 63);
  const int bg = tid >> 6;
  const int b0 = blockIdx.y * 64;

  __shared__ float4 rs4[64][32];
  for (int idx = tid; idx < 2048; idx += 256) {
    int bb = idx >> 5, q = idx & 31;
    rs4[bb][q] = ((const float4*)rr)[(size_t)(b0 + bb) * 32 + q];
  }
  __syncthreads();

  float acc[16];
#pragma unroll
  for (int m = 0; m < 16; ++m) acc[m] = 0.0f;

  for (int h4 = 0; h4 < 32; ++h4) {
    float w0 = Wout[(size_t)(4 * h4 + 0) * VV + v];
    float w1 = Wout[(size_t)(4 * h4 + 1) * VV + v];
    float w2 = Wout[(size_t)(4 * h4 + 2) * VV + v];
    float w3 = Wout[(size_t)(4 * h4 + 3) * VV + v];
#pragma unroll
    for (int m = 0; m < 16; ++m) {
      float4 rv = rs4[bg * 16 + m][h4];
      float t = rv.x * w0;
      t = fmaf(rv.y, w1, t);
      t = fmaf(rv.z, w2, t);
      t = fmaf(rv.w, w3, t);
      acc[m] += t;
    }
  }
  float bo = bout[v];
#pragma unroll
  for (int m = 0; m < 16; ++m) {
    out[(size_t)(b0 + bg * 16 + m) * VV + v] = acc[m] + bo;
  }
}

// ---------------------------------------------------------------------------
extern "C" void kernel_launch(void* const* d_in, const int* in_sizes, int n_in,
                              void* d_out, int out_size, void* d_ws, size_t ws_size,
                              hipStream_t stream)
{
  const int* seq      = (const int*)d_in[0];
  const float* embed  = (const float*)d_in[1];
  const float* W1     = (const float*)d_in[2];
  const float* b1     = (const float*)d_in[3];
  const float* W2     = (const float*)d_in[4];
  const float* b2     = (const float*)d_in[5];
  const float* gamma  = (const float*)d_in[6];
  const float* beta   = (const float*)d_in[7];
  const float* Wrp    = (const float*)d_in[8];
  const float* brp    = (const float*)d_in[9];
  const float* Wout   = (const float*)d_in[10];
  const float* bout   = (const float*)d_in[11];
  float* out          = (float*)d_out;

  char* ws = (char*)d_ws;
  float* Htab2 = (float*)ws;                         // 32000*136*4 = 17,408,000 B
  float* rr    = (float*)(ws + 17408000);            //    131,072 B

  hipLaunchKernelGGL(build_htab_kernel, dim3(256), dim3(256), 0, stream,
                     embed, W1, b1, W2, b2, gamma, beta, Htab2);
  hipLaunchKernelGGL(scan_kernel, dim3(BB), dim3(512), 0, stream,
                     seq, Htab2, Wrp, brp, rr);
  hipLaunchKernelGGL(out_kernel, dim3(VV / 64, 4), dim3(256), 0, stream,
                     rr, Wout, bout, out);
}

// Round 10
// 1459.885 us; speedup vs baseline: 1.1500x; 1.1500x over previous
//
#include <hip/hip_runtime.h>
#include <hip/hip_bf16.h>

// B=256, L=2048, H=128, V=32000, THR=0.4, LN_EPS=1e-5. All fp32.
// Htab2 row (RS=136 floats): [0:64)=h[0..63], [64:68)=pad, [68:132)=h[64..127],
// [132]=kk, [133]=inv.
// Scan v7b: R=4/C=8 ownership to cut the per-step LDS k-broadcast (v7 design,
// codegen-safe: all inline-asm operands are NAMED locals — no arrays/aggregates
// touch asm, fixing "tied indirect register inputs").
// Thread (wv=tid>>6, rg=(lane)>>4, cg=lane&15) owns rows i0..i0+3
// (i0=wv*16+rg*4) x cols [cg*8,cg*8+8). k-refill = 32B cols + 16B ki4 + 8B
// kk/inv per thread (vs 140B in v4) -> LDS/step/CU 64KB -> 28KB.
// Row dot completes inside the 16-lane cg-group: xor1(0xB1)+xor2(0x4E)+
// half_mirror(0x141)+mirror(0x140) -> full sums in all 16 lanes (mirror ops
// exact on quad/half-uniform data; kernel-A-verified semantics). ||e||^2:
// local 4-row sum is cg-uniform; BCAST15(0x142)+BCAST31(0x143) put the wave
// total in lanes 48-63; lane 63 writes red_s. Step skeleton = v4 verbatim
// (matvec pre-barrier, lgkm-only barrier, post: red read -> vmcnt(3) ->
// refill -> gate -> update). 8-slot ring, lead-4 DMA. No sched_barrier.

#define BB 256
#define LL 2048
#define HH 128
#define VV 32000
#define RS 136

typedef float f32x2 __attribute__((ext_vector_type(2)));

__device__ __forceinline__ void dma16(const float* g, float* l) {
  __builtin_amdgcn_global_load_lds(
      (const __attribute__((address_space(1))) void*)g,
      (__attribute__((address_space(3))) void*)l,
      16, 0, 0);
}

template <int CTRL>
__device__ __forceinline__ float dppadd(float x) {
  int y = __builtin_amdgcn_update_dpp(0, __float_as_int(x), CTRL, 0xF, 0xF, true);
  return x + __int_as_float(y);
}

// d = a*b + d  (packed 2x fp32)
__device__ __forceinline__ void pkfma(f32x2& d, f32x2 a, f32x2 b) {
  asm("v_pk_fma_f32 %0, %1, %2, %0" : "+v"(d) : "v"(a), "v"(b));
}

__device__ __forceinline__ void barrier_lgkm() {
  asm volatile("s_waitcnt lgkmcnt(0)\n\ts_barrier" ::: "memory");
}
__device__ __forceinline__ void wait_vmN(int n) {
  if (n == 3)      asm volatile("s_waitcnt vmcnt(3)" ::: "memory");
  else if (n == 2) asm volatile("s_waitcnt vmcnt(2)" ::: "memory");
  else if (n == 1) asm volatile("s_waitcnt vmcnt(1)" ::: "memory");
  else             asm volatile("s_waitcnt vmcnt(0)" ::: "memory");
}

// ---------------------------------------------------------------------------
// Kernel A: Htab2 row = LN(e + relu(e@W1+b1)@W2 + b2) (+ kk, inv), padded.
// (unchanged from verified baseline)
// ---------------------------------------------------------------------------
__global__ __launch_bounds__(256, 1) void build_htab_kernel(
    const float* __restrict__ embed,
    const float* __restrict__ W1,
    const float* __restrict__ b1,
    const float* __restrict__ W2,
    const float* __restrict__ b2,
    const float* __restrict__ gamma,
    const float* __restrict__ beta,
    float* __restrict__ Htab2)
{
  const int tid = threadIdx.x;
  const int j   = tid & 127;
  const int h2  = tid >> 7;

  float w1r[128];
#pragma unroll
  for (int m = 0; m < 128; ++m) w1r[m] = W1[m * 256 + tid];

  const float b1n = b1[tid];
  const float b2j = b2[j];
  const float gj  = gamma[j];
  const float bj  = beta[j];

  __shared__ __align__(16) float4 w2q[64][128];   // 128 KiB
  __shared__ __align__(16) float e_s[128];
  __shared__ __align__(16) float a_s[256];
  __shared__ float p_s[2][128];
  __shared__ float red[8];

  for (int idx = tid; idx < 8192; idx += 256) {
    int n4 = idx >> 7, jj = idx & 127;
    float4 w;
    w.x = W2[(size_t)(4 * n4 + 0) * 128 + jj];
    w.y = W2[(size_t)(4 * n4 + 1) * 128 + jj];
    w.z = W2[(size_t)(4 * n4 + 2) * 128 + jj];
    w.w = W2[(size_t)(4 * n4 + 3) * 128 + jj];
    w2q[n4][jj] = w;
  }
  __syncthreads();

  for (int v = blockIdx.x; v < VV; v += gridDim.x) {
    if (tid < 128) e_s[tid] = embed[(size_t)v * 128 + tid];
    __syncthreads();

    float acc[4] = {b1n, 0.f, 0.f, 0.f};
#pragma unroll
    for (int q = 0; q < 32; ++q) {
      float4 ev = *(const float4*)&e_s[4 * q];
      float t = ev.x * w1r[4 * q + 0];
      t = fmaf(ev.y, w1r[4 * q + 1], t);
      t = fmaf(ev.z, w1r[4 * q + 2], t);
      t = fmaf(ev.w, w1r[4 * q + 3], t);
      acc[q & 3] += t;
    }
    float a = fmaxf((acc[0] + acc[1]) + (acc[2] + acc[3]), 0.0f);
    a_s[tid] = a;
    __syncthreads();

    float p0 = 0.f, p1 = 0.f, p2v = 0.f, p3 = 0.f;
#pragma unroll
    for (int q = 0; q < 32; ++q) {
      int n4 = h2 * 32 + q;
      float4 av = *(const float4*)&a_s[4 * n4];
      float4 wq = w2q[n4][j];
      p0 = fmaf(av.x, wq.x, p0);
      p1 = fmaf(av.y, wq.y, p1);
      p2v = fmaf(av.z, wq.z, p2v);
      p3 = fmaf(av.w, wq.w, p3);
    }
    p_s[h2][j] = (p0 + p1) + (p2v + p3);
    __syncthreads();

    float y = 0.0f;
    if (tid < 128) {
      float ff = p_s[0][tid] + p_s[1][tid] + b2j;
      y = e_s[tid] + ff;
    }
    float s1 = y, s2 = y * y;
    s1 = dppadd<0xB1>(s1);  s2 = dppadd<0xB1>(s2);
    s1 = dppadd<0x4E>(s1);  s2 = dppadd<0x4E>(s2);
    s1 = dppadd<0x141>(s1); s2 = dppadd<0x141>(s2);
    s1 = dppadd<0x140>(s1); s2 = dppadd<0x140>(s2);
    s1 = dppadd<0x142>(s1); s2 = dppadd<0x142>(s2);
    s1 = dppadd<0x143>(s1); s2 = dppadd<0x143>(s2);
    if (tid < 128 && (tid & 63) == 63) {
      red[tid >> 6] = s1;
      red[2 + (tid >> 6)] = s2;
    }
    __syncthreads();
    float mu = (red[0] + red[1]) * (1.0f / 128.0f);
    float ms = (red[2] + red[3]) * (1.0f / 128.0f);
    float var = ms - mu * mu;
    float hv = 0.0f;
    if (tid < 128) {
      float dy = y - mu;
      hv = dy * (1.0f / sqrtf(var + 1e-5f)) * gj + bj;
      int ofs = tid + ((tid >> 6) << 2);           // padded layout
      Htab2[(size_t)v * RS + ofs] = hv;
    }
    float q2 = hv * hv;
    q2 = dppadd<0xB1>(q2);
    q2 = dppadd<0x4E>(q2);
    q2 = dppadd<0x141>(q2);
    q2 = dppadd<0x140>(q2);
    q2 = dppadd<0x142>(q2);
    q2 = dppadd<0x143>(q2);
    if (tid < 128 && (tid & 63) == 63) red[4 + (tid >> 6)] = q2;
    __syncthreads();
    if (tid == 0) {
      float kk = red[4] + red[5];
      Htab2[(size_t)v * RS + 132] = kk;
      Htab2[(size_t)v * RS + 133] = 1.0f / (kk + 1e-6f);
    }
    __syncthreads();
  }
}

// ---------------------------------------------------------------------------
// Kernel B: per-batch scan, R=4/C=8 layout. 256 blocks x 512 threads.
// Slot t&7 holds k_t; step t issues DMA k_{t+4} -> slot (t+4)&7; post-barrier
// vmcnt(3) retires exactly k_{t+1}, which the refill then reads.
// ---------------------------------------------------------------------------
__global__ __launch_bounds__(512, 1) void scan_kernel(
    const int* __restrict__ seq,
    const float* __restrict__ Htab2,
    const float* __restrict__ Wrp,
    const float* __restrict__ brp,
    float* __restrict__ rr)
{
  const int b     = blockIdx.x;
  const int tid   = threadIdx.x;
  const int lane  = tid & 63;
  const int wv    = tid >> 6;               // wave 0..7
  const int rg    = lane >> 4;              // row-group within wave (0..3)
  const int cg    = lane & 15;              // col-group (0..15)
  const int i0    = wv * 16 + rg * 4;       // first owned row
  const int iofs  = i0 + ((i0 >> 6) << 2);  // padded float-offset of rows i0..i0+3
  const int kbase = (cg & 7) * 8 + (cg >> 3) * 68;  // own 8 cols float-offset

  __shared__ int seq_s[LL];
  __shared__ __align__(16) float slots[8][RS];
  __shared__ __align__(16) float red_s[4][8];
  __shared__ __align__(16) float r_s[128];
  __shared__ float p2_s[4][128];

  // prologue DMAs: k0..k3 -> slots 0..3 (every wave issues its own copy)
  {
    int t0 = seq[(size_t)b * LL + 0];
    int t1 = seq[(size_t)b * LL + 1];
    int t2 = seq[(size_t)b * LL + 2];
    int t3 = seq[(size_t)b * LL + 3];
    if (lane < 34) {
      dma16(Htab2 + (size_t)t0 * RS + lane * 4, &slots[0][0]);
      dma16(Htab2 + (size_t)t1 * RS + lane * 4, &slots[1][0]);
      dma16(Htab2 + (size_t)t2 * RS + lane * 4, &slots[2][0]);
      dma16(Htab2 + (size_t)t3 * RS + lane * 4, &slots[3][0]);
    }
  }
  for (int t = tid; t < LL; t += 512) seq_s[t] = seq[(size_t)b * LL + t];
  __syncthreads();   // full drain (incl. prologue DMAs) — once, at start

  // M[row j][col pair m] as 16 NAMED f32x2 (asm-safe: no arrays touch asm)
  f32x2 M00{0.f,0.f}, M01{0.f,0.f}, M02{0.f,0.f}, M03{0.f,0.f};
  f32x2 M10{0.f,0.f}, M11{0.f,0.f}, M12{0.f,0.f}, M13{0.f,0.f};
  f32x2 M20{0.f,0.f}, M21{0.f,0.f}, M22{0.f,0.f}, M23{0.f,0.f};
  f32x2 M30{0.f,0.f}, M31{0.f,0.f}, M32{0.f,0.f}, M33{0.f,0.f};

  f32x2 kA0, kA1, kA2, kA3, kB0, kB1, kB2, kB3;
  float4 kiA, kiB;
  float kkA, invA, kkB, invB;
  {
    const f32x2* kp = (const f32x2*)&slots[0][kbase];
    kA0 = kp[0]; kA1 = kp[1]; kA2 = kp[2]; kA3 = kp[3];
    kiA = *(const float4*)&slots[0][iofs];
    float2 kv = *(const float2*)&slots[0][132];
    kkA = kv.x; invA = kv.y;
    asm volatile("" : "+v"(kA0), "+v"(kA1), "+v"(kA2), "+v"(kA3));
    asm volatile("" : "+v"(kiA.x), "+v"(kiA.y), "+v"(kiA.z), "+v"(kiA.w));
    asm volatile("" : "+v"(kkA), "+v"(invA));
  }

  // nwait==3: issue DMA k_{t+4} into slot sd, wait vmcnt(3).
  // nwait<3 : tail, no issue, wait vmcnt(nwait).
  auto step = [&](f32x2& kc0, f32x2& kc1, f32x2& kc2, f32x2& kc3,
                  float4& kic, float kk_c, float inv_c,
                  f32x2& kn0, f32x2& kn1, f32x2& kn2, f32x2& kn3,
                  float4& kin, float& kk_n, float& inv_n,
                  int t, int p, int sn, int sd, int nwait) {
    if (nwait == 3) {
      int tk = seq_s[t + 4];
      if (lane < 34)
        dma16(Htab2 + (size_t)tk * RS + lane * 4, &slots[sd][0]);
    }
    // matvec: 4 rows x own 8 cols
    f32x2 a0{0.f,0.f}, a1{0.f,0.f}, a2{0.f,0.f}, a3{0.f,0.f};
    pkfma(a0, kc0, M00); pkfma(a0, kc1, M01); pkfma(a0, kc2, M02); pkfma(a0, kc3, M03);
    pkfma(a1, kc0, M10); pkfma(a1, kc1, M11); pkfma(a1, kc2, M12); pkfma(a1, kc3, M13);
    pkfma(a2, kc0, M20); pkfma(a2, kc1, M21); pkfma(a2, kc2, M22); pkfma(a2, kc3, M23);
    pkfma(a3, kc0, M30); pkfma(a3, kc1, M31); pkfma(a3, kc2, M32); pkfma(a3, kc3, M33);
    float v0 = a0.x + a0.y, v1 = a1.x + a1.y;
    float v2 = a2.x + a2.y, v3 = a3.x + a3.y;
    // full row-dot across the 16 cg-lanes; result in ALL 16 lanes
    v0 = dppadd<0xB1>(v0);  v1 = dppadd<0xB1>(v1);
    v2 = dppadd<0xB1>(v2);  v3 = dppadd<0xB1>(v3);
    v0 = dppadd<0x4E>(v0);  v1 = dppadd<0x4E>(v1);
    v2 = dppadd<0x4E>(v2);  v3 = dppadd<0x4E>(v3);
    v0 = dppadd<0x141>(v0); v1 = dppadd<0x141>(v1);
    v2 = dppadd<0x141>(v2); v3 = dppadd<0x141>(v3);
    v0 = dppadd<0x140>(v0); v1 = dppadd<0x140>(v1);
    v2 = dppadd<0x140>(v2); v3 = dppadd<0x140>(v3);
    float e0 = fmaf(-v0, inv_c, kic.x);
    float e1 = fmaf(-v1, inv_c, kic.y);
    float e2 = fmaf(-v2, inv_c, kic.z);
    float e3 = fmaf(-v3, inv_c, kic.w);
    // ||e||^2: local 4-row sum (cg-uniform), BCAST tree; total in lanes 48-63
    float s = fmaf(e3, e3, fmaf(e2, e2, fmaf(e1, e1, e0 * e0)));
    s = dppadd<0x142>(s);
    s = dppadd<0x143>(s);
    if (lane == 63) red_s[p][wv] = s;
    barrier_lgkm();                        // lgkmcnt(0)+s_barrier, NO vmcnt drain

    float4 ra = *(const float4*)&red_s[p][0];  // issue early: overlaps refill
    float4 rb = *(const float4*)&red_s[p][4];
    wait_vmN(nwait);
    {                                      // refill k_{t+1} (consumed next step)
      const f32x2* kp = (const f32x2*)&slots[sn][kbase];
      kn0 = kp[0]; kn1 = kp[1]; kn2 = kp[2]; kn3 = kp[3];
      kin = *(const float4*)&slots[sn][iofs];
      float2 kv = *(const float2*)&slots[sn][132];
      kk_n = kv.x; inv_n = kv.y;
    }
    float ne2 = ((ra.x + ra.y) + (ra.z + ra.w)) + ((rb.x + rb.y) + (rb.z + rb.w));
    int g = ne2 > 0.16f * kk_c;            // ||e|| > 0.4*||v||  (squared form)
    float ge0 = g ? e0 : 0.0f;
    float ge1 = g ? e1 : 0.0f;
    float ge2 = g ? e2 : 0.0f;
    float ge3 = g ? e3 : 0.0f;
    f32x2 g0{ge0, ge0}, g1{ge1, ge1}, g2{ge2, ge2}, g3{ge3, ge3};
    pkfma(M00, g0, kc0); pkfma(M01, g0, kc1); pkfma(M02, g0, kc2); pkfma(M03, g0, kc3);
    pkfma(M10, g1, kc0); pkfma(M11, g1, kc1); pkfma(M12, g1, kc2); pkfma(M13, g1, kc3);
    pkfma(M20, g2, kc0); pkfma(M21, g2, kc1); pkfma(M22, g2, kc2); pkfma(M23, g2, kc3);
    pkfma(M30, g3, kc0); pkfma(M31, g3, kc1); pkfma(M32, g3, kc2); pkfma(M33, g3, kc3);
    // pin refilled regs AFTER the update so loads hide under red-read + update
    asm volatile("" : "+v"(kn0), "+v"(kn1), "+v"(kn2), "+v"(kn3));
    asm volatile("" : "+v"(kin.x), "+v"(kin.y), "+v"(kin.z), "+v"(kin.w));
    asm volatile("" : "+v"(kk_n), "+v"(inv_n));
  };

  // steps 0..2039 (2040 = 8*255). Slot t&7 holds k_t; DMA fills (t+4)&7.
  for (int t = 0; t < 2040; t += 8) {
    step(kA0,kA1,kA2,kA3, kiA, kkA, invA, kB0,kB1,kB2,kB3, kiB, kkB, invB, t + 0, 0, 1, 4, 3);
    step(kB0,kB1,kB2,kB3, kiB, kkB, invB, kA0,kA1,kA2,kA3, kiA, kkA, invA, t + 1, 1, 2, 5, 3);
    step(kA0,kA1,kA2,kA3, kiA, kkA, invA, kB0,kB1,kB2,kB3, kiB, kkB, invB, t + 2, 2, 3, 6, 3);
    step(kB0,kB1,kB2,kB3, kiB, kkB, invB, kA0,kA1,kA2,kA3, kiA, kkA, invA, t + 3, 3, 4, 7, 3);
    step(kA0,kA1,kA2,kA3, kiA, kkA, invA, kB0,kB1,kB2,kB3, kiB, kkB, invB, t + 4, 0, 5, 0, 3);
    step(kB0,kB1,kB2,kB3, kiB, kkB, invB, kA0,kA1,kA2,kA3, kiA, kkA, invA, t + 5, 1, 6, 1, 3);
    step(kA0,kA1,kA2,kA3, kiA, kkA, invA, kB0,kB1,kB2,kB3, kiB, kkB, invB, t + 6, 2, 7, 2, 3);
    step(kB0,kB1,kB2,kB3, kiB, kkB, invB, kA0,kA1,kA2,kA3, kiA, kkA, invA, t + 7, 3, 0, 3, 3);
  }
  // tail: steps 2040..2046; last DMA at t=2043 (k_2047); drain vmcnt 3 -> 0
  step(kA0,kA1,kA2,kA3, kiA, kkA, invA, kB0,kB1,kB2,kB3, kiB, kkB, invB, 2040, 0, 1, 4, 3);
  step(kB0,kB1,kB2,kB3, kiB, kkB, invB, kA0,kA1,kA2,kA3, kiA, kkA, invA, 2041, 1, 2, 5, 3);
  step(kA0,kA1,kA2,kA3, kiA, kkA, invA, kB0,kB1,kB2,kB3, kiB, kkB, invB, 2042, 2, 3, 6, 3);
  step(kB0,kB1,kB2,kB3, kiB, kkB, invB, kA0,kA1,kA2,kA3, kiA, kkA, invA, 2043, 3, 4, 7, 3);
  step(kA0,kA1,kA2,kA3, kiA, kkA, invA, kB0,kB1,kB2,kB3, kiB, kkB, invB, 2044, 0, 5, 0, 2);
  step(kB0,kB1,kB2,kB3, kiB, kkB, invB, kA0,kA1,kA2,kA3, kiA, kkA, invA, 2045, 1, 6, 1, 1);
  step(kA0,kA1,kA2,kA3, kiA, kkA, invA, kB0,kB1,kB2,kB3, kiB, kkB, invB, 2046, 2, 7, 2, 0);

  // r = M_fin @ h(seq[b, L-1])  (kB = k_2047)
  {
    f32x2 a0{0.f,0.f}, a1{0.f,0.f}, a2{0.f,0.f}, a3{0.f,0.f};
    pkfma(a0, kB0, M00); pkfma(a0, kB1, M01); pkfma(a0, kB2, M02); pkfma(a0, kB3, M03);
    pkfma(a1, kB0, M10); pkfma(a1, kB1, M11); pkfma(a1, kB2, M12); pkfma(a1, kB3, M13);
    pkfma(a2, kB0, M20); pkfma(a2, kB1, M21); pkfma(a2, kB2, M22); pkfma(a2, kB3, M23);
    pkfma(a3, kB0, M30); pkfma(a3, kB1, M31); pkfma(a3, kB2, M32); pkfma(a3, kB3, M33);
    float v0 = a0.x + a0.y, v1 = a1.x + a1.y;
    float v2 = a2.x + a2.y, v3 = a3.x + a3.y;
    v0 = dppadd<0xB1>(v0);  v1 = dppadd<0xB1>(v1);
    v2 = dppadd<0xB1>(v2);  v3 = dppadd<0xB1>(v3);
    v0 = dppadd<0x4E>(v0);  v1 = dppadd<0x4E>(v1);
    v2 = dppadd<0x4E>(v2);  v3 = dppadd<0x4E>(v3);
    v0 = dppadd<0x141>(v0); v1 = dppadd<0x141>(v1);
    v2 = dppadd<0x141>(v2); v3 = dppadd<0x141>(v3);
    v0 = dppadd<0x140>(v0); v1 = dppadd<0x140>(v1);
    v2 = dppadd<0x140>(v2); v3 = dppadd<0x140>(v3);
    if (cg == 0) {
      *(float4*)&r_s[i0] = float4{v0, v1, v2, v3};
    }
  }
  __syncthreads();

  // rr[b,:] = r @ Wrp + brp  (512 threads: 4 row-groups of 32)
  const int j = tid & 127;
  const int g = tid >> 7;
  float pac[2] = {0.f, 0.f};
#pragma unroll
  for (int m = 0; m < 32; ++m) {
    pac[m & 1] = fmaf(r_s[g * 32 + m],
                      Wrp[(size_t)(g * 32 + m) * 128 + j], pac[m & 1]);
  }
  p2_s[g][j] = pac[0] + pac[1];
  __syncthreads();
  if (tid < 128) {
    rr[(size_t)b * 128 + tid] =
        p2_s[0][tid] + p2_s[1][tid] + p2_s[2][tid] + p2_s[3][tid] + brp[tid];
  }
}

// ---------------------------------------------------------------------------
// Kernel C: out[b,v] = rr[b,:] @ Wout[:,v] + bout[v]  (unchanged)
// ---------------------------------------------------------------------------
__global__ __launch_bounds__(256, 1) void out_kernel(
    const float* __restrict__ rr,
    const float* __restrict__ Wout,
    const float* __restrict__ bout,
    float* __restrict__ out)
{
  const int tid = threadIdx.x;
  const int v = blockIdx.x * 64 + (tid & 63);
  const int bg = tid >> 6;
  const int b0 = blockIdx.y * 64;

  __shared__ float4 rs4[64][32];
  for (int idx = tid; idx < 2048; idx += 256) {
    int bb = idx >> 5, q = idx & 31;
    rs4[bb][q] = ((const float4*)rr)[(size_t)(b0 + bb) * 32 + q];
  }
  __syncthreads();

  float acc[16];
#pragma unroll
  for (int m = 0; m < 16; ++m) acc[m] = 0.0f;

  for (int h4 = 0; h4 < 32; ++h4) {
    float w0 = Wout[(size_t)(4 * h4 + 0) * VV + v];
    float w1 = Wout[(size_t)(4 * h4 + 1) * VV + v];
    float w2 = Wout[(size_t)(4 * h4 + 2) * VV + v];
    float w3 = Wout[(size_t)(4 * h4 + 3) * VV + v];
#pragma unroll
    for (int m = 0; m < 16; ++m) {
      float4 rv = rs4[bg * 16 + m][h4];
      float t = rv.x * w0;
      t = fmaf(rv.y, w1, t);
      t = fmaf(rv.z, w2, t);
      t = fmaf(rv.w, w3, t);
      acc[m] += t;
    }
  }
  float bo = bout[v];
#pragma unroll
  for (int m = 0; m < 16; ++m) {
    out[(size_t)(b0 + bg * 16 + m) * VV + v] = acc[m] + bo;
  }
}

// ---------------------------------------------------------------------------
extern "C" void kernel_launch(void* const* d_in, const int* in_sizes, int n_in,
                              void* d_out, int out_size, void* d_ws, size_t ws_size,
                              hipStream_t stream)
{
  const int* seq      = (const int*)d_in[0];
  const float* embed  = (const float*)d_in[1];
  const float* W1     = (const float*)d_in[2];
  const float* b1     = (const float*)d_in[3];
  const float* W2     = (const float*)d_in[4];
  const float* b2     = (const float*)d_in[5];
  const float* gamma  = (const float*)d_in[6];
  const float* beta   = (const float*)d_in[7];
  const float* Wrp    = (const float*)d_in[8];
  const float* brp    = (const float*)d_in[9];
  const float* Wout   = (const float*)d_in[10];
  const float* bout   = (const float*)d_in[11];
  float* out          = (float*)d_out;

  char* ws = (char*)d_ws;
  float* Htab2 = (float*)ws;                         // 32000*136*4 = 17,408,000 B
  float* rr    = (float*)(ws + 17408000);            //    131,072 B

  hipLaunchKernelGGL(build_htab_kernel, dim3(256), dim3(256), 0, stream,
                     embed, W1, b1, W2, b2, gamma, beta, Htab2);
  hipLaunchKernelGGL(scan_kernel, dim3(BB), dim3(512), 0, stream,
                     seq, Htab2, Wrp, brp, rr);
  hipLaunchKernelGGL(out_kernel, dim3(VV / 64, 4), dim3(256), 0, stream,
                     rr, Wout, bout, out);
}